// Round 10
// baseline (193.928 us; speedup 1.0000x reference)
//
#include <hip/hip_runtime.h>
#include <hip/hip_fp16.h>

#define F 64
#define NBMAX 1024     // max dst-buckets (256 nodes each) -> supports N <= 262144
#define CHUNK 8192     // edges per partition block (longer per-bucket write runs)
#define CAPSH 13       // bucket capacity = 8192 slots (mean fill ~2560 + align pad <=768)
#define CAP (1 << CAPSH)
#define MMROWS 128
#define XT_PAD 132
#define GMN 64         // nodes per fused gather_mm block

typedef float __attribute__((ext_vector_type(4))) f4nt;

// Cache-policy lessons (measured):
//  R7: NT store of FINAL output only -> -9 us (win; keeps g2 table in L2)
//  R8: NT loads + scattered 4B NT part stores -> +38 us (8x write amplification)
//  R9: NT store of g1/g2 intermediates -> +7.4 us (B/C/D re-read them soon)
// => NT is used ONLY for the final output stream below.

// ---- A: dual-role kernel. Blocks [0,PG) partition edges into fixed-stride
// dst-buckets; blocks [PG,PG+MMG) compute g1 = x@W1 (fp16, UNSCALED — dinv
// applied later in build_bucket). The two tasks are data-independent.
__global__ __launch_bounds__(256) void part_mm(const int* __restrict__ src,
                                               const int* __restrict__ dst,
                                               unsigned* __restrict__ bcnt,
                                               unsigned* __restrict__ part,
                                               int E, int NB, int PG,
                                               const float* __restrict__ Xf,
                                               const float* __restrict__ W,
                                               __half2* __restrict__ Y, int N) {
    __shared__ float4 smem4[3136];   // 50176 B union
    int t = threadIdx.x;
    if ((int)blockIdx.x < PG) {
        // ---- partition role: lh 4KB + lbase 4KB + dch 32KB = 40KB ----
        unsigned* lh    = (unsigned*)smem4;          // NBMAX
        unsigned* lbase = lh + NBMAX;                // NBMAX
        int*      dch   = (int*)(lbase + NBMAX);     // CHUNK dst cache (32 KB)
        int e0 = blockIdx.x * CHUNK;
        int nch = min(CHUNK, E - e0);
        for (int b = t; b < NB; b += 256) lh[b] = 0;
        for (int i = t; i < nch; i += 256) dch[i] = dst[e0 + i];
        __syncthreads();
        for (int i = t; i < nch; i += 256)
            atomicAdd(&lh[((unsigned)dch[i]) >> 8], 1u);
        __syncthreads();
        for (int b = t; b < NB; b += 256) {
            unsigned c = lh[b];
            lbase[b] = c ? atomicAdd(&bcnt[b], c) : 0u;
            lh[b] = 0;  // reuse as local cursor
        }
        __syncthreads();
        for (int i = t; i < nch; i += 256) {
            unsigned d = (unsigned)dch[i];
            unsigned b = d >> 8;
            unsigned pos = lbase[b] + atomicAdd(&lh[b], 1u);
            if (pos < CAP)
                part[((size_t)b << CAPSH) + pos] = ((d & 255u) << 24) | (unsigned)src[e0 + i];
        }
        return;
    }
    // ---- mm role ----
    float* Ws = (float*)smem4;       // 4096 floats
    float* XT = Ws + 4096;           // 64*XT_PAD floats
    for (int i = t; i < 1024; i += 256)
        ((float4*)Ws)[i] = ((const float4*)W)[i];
    int row0 = ((int)blockIdx.x - PG) * MMROWS;
    for (int i = t; i < MMROWS * 16; i += 256) {
        int r = i >> 4, kc = (i & 15) * 4;
        float4 v = make_float4(0.f, 0.f, 0.f, 0.f);
        int gr = row0 + r;
        if (gr < N) v = *(const float4*)(Xf + (size_t)gr * F + kc);
        XT[(kc + 0) * XT_PAD + r] = v.x;
        XT[(kc + 1) * XT_PAD + r] = v.y;
        XT[(kc + 2) * XT_PAD + r] = v.z;
        XT[(kc + 3) * XT_PAD + r] = v.w;
    }
    __syncthreads();
    int ty = t >> 3, tx = t & 7;
    float acc[4][8];
#pragma unroll
    for (int i = 0; i < 4; ++i)
#pragma unroll
        for (int j = 0; j < 8; ++j) acc[i][j] = 0.f;
#pragma unroll 4
    for (int k = 0; k < 64; ++k) {
        float4 xr = *(const float4*)&XT[k * XT_PAD + ty * 4];
        float4 w0 = *(const float4*)&Ws[k * 64 + tx * 8];
        float4 w1 = *(const float4*)&Ws[k * 64 + tx * 8 + 4];
        const float* xv = &xr.x;
#pragma unroll
        for (int i = 0; i < 4; ++i) {
            float xs = xv[i];
            acc[i][0] += xs * w0.x; acc[i][1] += xs * w0.y;
            acc[i][2] += xs * w0.z; acc[i][3] += xs * w0.w;
            acc[i][4] += xs * w1.x; acc[i][5] += xs * w1.y;
            acc[i][6] += xs * w1.z; acc[i][7] += xs * w1.w;
        }
    }
#pragma unroll
    for (int i = 0; i < 4; ++i) {
        int gr = row0 + ty * 4 + i;
        if (gr >= N) continue;
        __half2 h[4];
#pragma unroll
        for (int j = 0; j < 4; ++j)
            h[j] = __floats2half2_rn(acc[i][2 * j], acc[i][2 * j + 1]);
        *reinterpret_cast<uint4*>(Y + (size_t)gr * 32 + tx * 4) =
            *reinterpret_cast<uint4*>(h);
    }
}

// ---- B: per-bucket CSR build, 1024 threads. Segments padded to 4-slot (16 B)
// alignment. Emits desc(start,deg,dinv), csr_src, and scales this bucket's g1
// rows in place by dinv.
__global__ __launch_bounds__(1024) void build_bucket(const unsigned* __restrict__ part,
                                                     const unsigned* __restrict__ bcnt,
                                                     uint4* __restrict__ desc,
                                                     int* __restrict__ csr_src,
                                                     uint4* __restrict__ G,   // g1, scaled in place
                                                     int N) {
    __shared__ unsigned cnt[256], off[256], cur[256];
    __shared__ float dvl[256];
    int t = threadIdx.x;
    int b = blockIdx.x;
    unsigned m0 = (unsigned)b << CAPSH;
    unsigned m1 = m0 + min(bcnt[b], (unsigned)CAP);
    if (t < 256) cnt[t] = 0;
    __syncthreads();
    for (unsigned j = m0 + t; j < m1; j += 1024)
        atomicAdd(&cnt[part[j] >> 24], 1u);
    __syncthreads();
    if (t < 256) off[t] = (cnt[t] + 3u) & ~3u;   // pad segments to 4 slots
    __syncthreads();
    for (int o = 1; o < 256; o <<= 1) {
        unsigned add = 0;
        if (t < 256 && t >= o) add = off[t - o];
        __syncthreads();
        if (t < 256) off[t] += add;
        __syncthreads();
    }
    unsigned excl = 0;
    if (t < 256) excl = t ? off[t - 1] : 0u;
    __syncthreads();                 // all inclusive-scan reads done before overwrite
    int v0 = b << 8;
    if (t < 256) {
        off[t] = excl;
        cur[t] = 0;
        unsigned c = cnt[t];
        float di = rsqrtf((float)(c + 1u));
        dvl[t] = di;
        int v = v0 + t;
        if (v < N)
            desc[v] = make_uint4(m0 + excl, c, __float_as_uint(di), 0u);
    }
    __syncthreads();
    for (unsigned j = m0 + t; j < m1; j += 1024) {
        unsigned p = part[j];
        unsigned d = p >> 24;
        unsigned pos = atomicAdd(&cur[d], 1u);
        csr_src[m0 + off[d] + pos] = (int)(p & 0xFFFFFFu);
    }
    // ---- scale this bucket's 256 g1 rows by dinv (coalesced uint4 stream) ----
#pragma unroll
    for (int k = 0; k < 2; ++k) {
        int idx = t + k * 1024;           // uint4 index within bucket (2048 total)
        int r = idx >> 3;
        int vv = v0 + r;
        if (vv >= N) continue;
        float dv = dvl[r];
        uint4 u = G[(size_t)v0 * 8 + idx];
        __half2* hp = (__half2*)&u;
#pragma unroll
        for (int q = 0; q < 4; ++q) {
            float2 f = __half22float2(hp[q]);
            hp[q] = __floats2half2_rn(f.x * dv, f.y * dv);
        }
        G[(size_t)v0 * 8 + idx] = u;
    }
}

__device__ __forceinline__ void acc8(float* a, const uint4& u) {
    const __half2* hp = reinterpret_cast<const __half2*>(&u);
#pragma unroll
    for (int q = 0; q < 4; ++q) {
        float2 f = __half22float2(hp[q]);
        a[2 * q] += f.x;
        a[2 * q + 1] += f.y;
    }
}

// ---- C FUSED: out1[v] = relu(dinv_v * (sum g1[s] + g1[v]) + b1) ; g2 = (out1@W2)*dinv
// Gather phase: 8-edge unroll -> 16 uint4 loads in flight per lane (MLP).
__global__ __launch_bounds__(256, 4) void gather_mm(const int* __restrict__ csr_src,
                                                    const uint4* __restrict__ desc,
                                                    const uint4* __restrict__ G,
                                                    const float* __restrict__ bias,
                                                    const float* __restrict__ W,
                                                    __half* __restrict__ Y, int N) {
    __shared__ float Ws[64 * 64];     // 16 KB
    __shared__ __half XT[64 * 72];    // 9 KB
    __shared__ float dvs[64];
    int t = threadIdx.x;
    for (int i = t; i < 1024; i += 256)
        ((float4*)Ws)[i] = ((const float4*)W)[i];
    int v0 = blockIdx.x * GMN;
    {   // ---- phase 1: gather (int4 index loads; r0 is 16 B aligned) ----
        int grp = t >> 2, l4 = t & 3;
        int v = v0 + grp;
        float acc[16];
#pragma unroll
        for (int i = 0; i < 16; ++i) acc[i] = 0.f;
        float dv = 0.f;
        if (v < N) {
            uint4 nd = desc[v];
            unsigned r0 = nd.x, r1 = nd.x + nd.y;
            dv = __uint_as_float(nd.z);
            size_t gb = (size_t)v * 8 + l4 * 2;
            uint4 sa = G[gb], sb = G[gb + 1];   // self-loop term
            acc8(acc, sa); acc8(acc + 8, sb);
            unsigned j = r0;
            for (; j + 8 <= r1; j += 8) {       // 8-edge unroll: 16 loads in flight
                int4 s4a = *(const int4*)(csr_src + j);
                int4 s4b = *(const int4*)(csr_src + j + 4);
                const int s[8] = { s4a.x, s4a.y, s4a.z, s4a.w,
                                   s4b.x, s4b.y, s4b.z, s4b.w };
                uint4 u[8][2];
#pragma unroll
                for (int i = 0; i < 8; ++i) {
                    size_t base = (size_t)s[i] * 8 + l4 * 2;
                    u[i][0] = G[base]; u[i][1] = G[base + 1];
                }
#pragma unroll
                for (int i = 0; i < 8; ++i) { acc8(acc, u[i][0]); acc8(acc + 8, u[i][1]); }
            }
            if (j + 4 <= r1) {
                int4 s4 = *(const int4*)(csr_src + j);
                const int s[4] = { s4.x, s4.y, s4.z, s4.w };
                uint4 u[4][2];
#pragma unroll
                for (int i = 0; i < 4; ++i) {
                    size_t base = (size_t)s[i] * 8 + l4 * 2;
                    u[i][0] = G[base]; u[i][1] = G[base + 1];
                }
#pragma unroll
                for (int i = 0; i < 4; ++i) { acc8(acc, u[i][0]); acc8(acc + 8, u[i][1]); }
                j += 4;
            }
            for (; j < r1; ++j) {
                size_t base = (size_t)csr_src[j] * 8 + l4 * 2;
                uint4 a = G[base], b = G[base + 1];
                acc8(acc, a); acc8(acc + 8, b);
            }
        }
        if (l4 == 0) dvs[grp] = dv;
        __half h[16];
#pragma unroll
        for (int q = 0; q < 4; ++q) {
            float4 bb = ((const float4*)bias)[l4 * 4 + q];
            float r0_ = fmaxf(acc[4 * q + 0] * dv + bb.x, 0.f);
            float r1_ = fmaxf(acc[4 * q + 1] * dv + bb.y, 0.f);
            float r2_ = fmaxf(acc[4 * q + 2] * dv + bb.z, 0.f);
            float r3_ = fmaxf(acc[4 * q + 3] * dv + bb.w, 0.f);
            ((__half2*)h)[2 * q + 0] = __floats2half2_rn(r0_, r1_);
            ((__half2*)h)[2 * q + 1] = __floats2half2_rn(r2_, r3_);
        }
        *(uint4*)&XT[grp * 72 + l4 * 16] = ((uint4*)h)[0];
        *(uint4*)&XT[grp * 72 + l4 * 16 + 8] = ((uint4*)h)[1];
    }
    __syncthreads();
    // ---- phase 2: mm (2 rows x 8 cols per thread) ----
    int tx = t & 7, ty = t >> 3;
    const __half2* Xa = (const __half2*)&XT[ty * 72];
    const __half2* Xb = (const __half2*)&XT[(ty + 32) * 72];
    float a0[8], a1[8];
#pragma unroll
    for (int i = 0; i < 8; ++i) { a0[i] = 0.f; a1[i] = 0.f; }
#pragma unroll 4
    for (int k2 = 0; k2 < 32; ++k2) {
        float2 f0 = __half22float2(Xa[k2]);
        float2 f1 = __half22float2(Xb[k2]);
        int k = 2 * k2;
        float4 w00 = *(const float4*)&Ws[k * 64 + tx * 8];
        float4 w01 = *(const float4*)&Ws[k * 64 + tx * 8 + 4];
        float4 w10 = *(const float4*)&Ws[(k + 1) * 64 + tx * 8];
        float4 w11 = *(const float4*)&Ws[(k + 1) * 64 + tx * 8 + 4];
        a0[0] += f0.x * w00.x + f0.y * w10.x; a0[1] += f0.x * w00.y + f0.y * w10.y;
        a0[2] += f0.x * w00.z + f0.y * w10.z; a0[3] += f0.x * w00.w + f0.y * w10.w;
        a0[4] += f0.x * w01.x + f0.y * w11.x; a0[5] += f0.x * w01.y + f0.y * w11.y;
        a0[6] += f0.x * w01.z + f0.y * w11.z; a0[7] += f0.x * w01.w + f0.y * w11.w;
        a1[0] += f1.x * w00.x + f1.y * w10.x; a1[1] += f1.x * w00.y + f1.y * w10.y;
        a1[2] += f1.x * w00.z + f1.y * w10.z; a1[3] += f1.x * w00.w + f1.y * w10.w;
        a1[4] += f1.x * w01.x + f1.y * w11.x; a1[5] += f1.x * w01.y + f1.y * w11.y;
        a1[6] += f1.x * w01.z + f1.y * w11.z; a1[7] += f1.x * w01.w + f1.y * w11.w;
    }
#pragma unroll
    for (int half_ = 0; half_ < 2; ++half_) {
        int r = ty + half_ * 32;
        int v = v0 + r;
        if (v >= N) continue;
        float dv = dvs[r];
        const float* a = half_ ? a1 : a0;
        __half2 h[4];
#pragma unroll
        for (int q = 0; q < 4; ++q)
            h[q] = __floats2half2_rn(a[2 * q] * dv, a[2 * q + 1] * dv);
        *(uint4*)(Y + (size_t)v * F + tx * 8) = *reinterpret_cast<uint4*>(h);
    }
}

// ---- D: final gather: out[v] = dinv[v]*(sum g2[s] + g2[v]) + b2 ; fp32 out
// (non-temporal output stores: don't evict the g2 table from L2).
#define ACCUM8(u) { \
    const __half2* hp = reinterpret_cast<const __half2*>(&(u)); \
    _Pragma("unroll") \
    for (int q = 0; q < 4; ++q) { \
        float2 f = __half22float2(hp[q]); \
        acc[2 * q] += f.x; acc[2 * q + 1] += f.y; } }

__global__ __launch_bounds__(256) void gather_out(const int* __restrict__ csr_src,
                                                  const uint4* __restrict__ desc,
                                                  const uint4* __restrict__ G,
                                                  const float* __restrict__ bias,
                                                  float* __restrict__ O, int N) {
    int gid = blockIdx.x * 256 + threadIdx.x;
    int v = gid >> 3;
    if (v >= N) return;
    int l8 = gid & 7;
    uint4 nd = desc[v];
    unsigned r0 = nd.x;
    unsigned r1 = r0 + nd.y;
    float dv = __uint_as_float(nd.z);
    float acc[8];
#pragma unroll
    for (int i = 0; i < 8; ++i) acc[i] = 0.f;
    {
        uint4 u = G[(size_t)v * 8 + l8];  // self-loop term
        ACCUM8(u)
    }
    unsigned j = r0;   // 16 B aligned
    for (; j + 8 <= r1; j += 8) {
        int4 sa = *(const int4*)(csr_src + j);
        int4 sb = *(const int4*)(csr_src + j + 4);
        const int s[8] = { sa.x, sa.y, sa.z, sa.w, sb.x, sb.y, sb.z, sb.w };
        uint4 u[8];
#pragma unroll
        for (int i = 0; i < 8; ++i) u[i] = G[(size_t)s[i] * 8 + l8];
#pragma unroll
        for (int i = 0; i < 8; ++i) ACCUM8(u[i])
    }
    if (j + 4 <= r1) {
        int4 sa = *(const int4*)(csr_src + j);
        const int s[4] = { sa.x, sa.y, sa.z, sa.w };
        uint4 u[4];
#pragma unroll
        for (int i = 0; i < 4; ++i) u[i] = G[(size_t)s[i] * 8 + l8];
#pragma unroll
        for (int i = 0; i < 4; ++i) ACCUM8(u[i])
        j += 4;
    }
    for (; j < r1; ++j) {
        uint4 u = G[(size_t)csr_src[j] * 8 + l8];
        ACCUM8(u)
    }
    float4 bb0 = ((const float4*)bias)[l8 * 2];
    float4 bb1 = ((const float4*)bias)[l8 * 2 + 1];
    f4nt* o = (f4nt*)O + (size_t)v * 16 + l8 * 2;
    f4nt o0 = { acc[0] * dv + bb0.x, acc[1] * dv + bb0.y,
                acc[2] * dv + bb0.z, acc[3] * dv + bb0.w };
    f4nt o1 = { acc[4] * dv + bb1.x, acc[5] * dv + bb1.y,
                acc[6] * dv + bb1.z, acc[7] * dv + bb1.w };
    __builtin_nontemporal_store(o0, o);
    __builtin_nontemporal_store(o1, o + 1);
}
#undef ACCUM8

extern "C" void kernel_launch(void* const* d_in, const int* in_sizes, int n_in,
                              void* d_out, int out_size, void* d_ws, size_t ws_size,
                              hipStream_t stream) {
    const float* x  = (const float*)d_in[0];
    const int*   ei = (const int*)d_in[1];
    const float* W1 = (const float*)d_in[2];
    const float* b1 = (const float*)d_in[3];
    const float* W2 = (const float*)d_in[4];
    const float* b2 = (const float*)d_in[5];
    int N = in_sizes[0] / F;
    int E = in_sizes[1] / 2;
    const int* srcp = ei;
    const int* dstp = ei + E;
    float* out = (float*)d_out;
    int NB = (N + 255) >> 8;

    char* w = (char*)d_ws;
    auto align = [](size_t s) { return (s + 255) / 256 * 256; };
    unsigned* bcnt    = (unsigned*)w;  w += align(NBMAX * 4);
    unsigned* part    = (unsigned*)w;  w += align((size_t)NB << (CAPSH + 2));
    int*      csrsrc  = (int*)w;       w += align((size_t)NB << (CAPSH + 2));
    uint4*    desc    = (uint4*)w;     w += align((size_t)N * 16);
    __half2*  bufA    = (__half2*)w;   w += align((size_t)N * F * 2);  // g1 (f16)
    __half*   bufC    = (__half*)w;    w += align((size_t)N * F * 2);  // g2 (f16)

    hipMemsetAsync(bcnt, 0, (size_t)NB * 4, stream);

    int PG = (E + CHUNK - 1) / CHUNK;
    int MMG = (N + MMROWS - 1) / MMROWS;
    // A: partition edges (blocks 0..PG) + g1 = x@W1 unscaled (blocks PG..PG+MMG)
    part_mm<<<PG + MMG, 256, 0, stream>>>(srcp, dstp, bcnt, part, E, NB, PG,
                                          x, W1, (__half2*)bufA, N);
    // B: CSR build (4-aligned segments) + desc + in-place dinv scaling of g1
    build_bucket<<<NB, 1024, 0, stream>>>(part, bcnt, desc, csrsrc, (uint4*)bufA, N);
    // C: out1 = relu(dinv*(sum g1)+b1); g2 = (out1@W2)*dinv
    gather_mm<<<(N + GMN - 1) / GMN, 256, 0, stream>>>(csrsrc, desc, (const uint4*)bufA, b1, W2, bufC, N);
    // D: out = dinv*(sum g2) + b2 (NT stores)
    gather_out<<<(int)(((size_t)N * 8 + 255) / 256), 256, 0, stream>>>(
        csrsrc, desc, (const uint4*)bufC, b2, out, N);
}

// Round 11
// 174.054 us; speedup vs baseline: 1.1142x; 1.1142x over previous
//
#include <hip/hip_runtime.h>
#include <hip/hip_fp16.h>

#define F 64
#define NBMAX 1024     // max dst-buckets (256 nodes each) -> supports N <= 262144
#define CHUNK 8192     // edges per partition block (longer per-bucket write runs)
#define CAPSH 13       // bucket capacity = 8192 slots (mean fill ~2560 + align pad <=768)
#define CAP (1 << CAPSH)
#define MMROWS 128
#define XT_PAD 132
#define GMN 64         // nodes per fused gather_mm block

typedef float __attribute__((ext_vector_type(4))) f4nt;

// Measured configuration ledger (dur_us total):
//  R7  = THIS SOURCE = 175.0 (best)
//  R1 baseline 184.2 | R4 185.7 | R3 192 | R10 8-edge-unroll 193.9 (L2 thrash,
//  FETCH 60->75MB) | R6 gather-then-MM 208 | R8 NT-everything 213.6 | R5
//  quartered tables 243.8 | R2 persistent fusion 335.6
// NT stores: final output ONLY (R7 win; R8/R9 extensions regressed).
// Gather unroll: 4 edges (R10's 8 thrashed L2).

// ---- A: dual-role kernel. Blocks [0,PG) partition edges into fixed-stride
// dst-buckets; blocks [PG,PG+MMG) compute g1 = x@W1 (fp16, UNSCALED — dinv
// applied later in build_bucket). The two tasks are data-independent.
__global__ __launch_bounds__(256) void part_mm(const int* __restrict__ src,
                                               const int* __restrict__ dst,
                                               unsigned* __restrict__ bcnt,
                                               unsigned* __restrict__ part,
                                               int E, int NB, int PG,
                                               const float* __restrict__ Xf,
                                               const float* __restrict__ W,
                                               __half2* __restrict__ Y, int N) {
    __shared__ float4 smem4[3136];   // 50176 B union
    int t = threadIdx.x;
    if ((int)blockIdx.x < PG) {
        // ---- partition role: lh 4KB + lbase 4KB + dch 32KB = 40KB ----
        unsigned* lh    = (unsigned*)smem4;          // NBMAX
        unsigned* lbase = lh + NBMAX;                // NBMAX
        int*      dch   = (int*)(lbase + NBMAX);     // CHUNK dst cache (32 KB)
        int e0 = blockIdx.x * CHUNK;
        int nch = min(CHUNK, E - e0);
        for (int b = t; b < NB; b += 256) lh[b] = 0;
        for (int i = t; i < nch; i += 256) dch[i] = dst[e0 + i];
        __syncthreads();
        for (int i = t; i < nch; i += 256)
            atomicAdd(&lh[((unsigned)dch[i]) >> 8], 1u);
        __syncthreads();
        for (int b = t; b < NB; b += 256) {
            unsigned c = lh[b];
            lbase[b] = c ? atomicAdd(&bcnt[b], c) : 0u;
            lh[b] = 0;  // reuse as local cursor
        }
        __syncthreads();
        for (int i = t; i < nch; i += 256) {
            unsigned d = (unsigned)dch[i];
            unsigned b = d >> 8;
            unsigned pos = lbase[b] + atomicAdd(&lh[b], 1u);
            if (pos < CAP)
                part[((size_t)b << CAPSH) + pos] = ((d & 255u) << 24) | (unsigned)src[e0 + i];
        }
        return;
    }
    // ---- mm role ----
    float* Ws = (float*)smem4;       // 4096 floats
    float* XT = Ws + 4096;           // 64*XT_PAD floats
    for (int i = t; i < 1024; i += 256)
        ((float4*)Ws)[i] = ((const float4*)W)[i];
    int row0 = ((int)blockIdx.x - PG) * MMROWS;
    for (int i = t; i < MMROWS * 16; i += 256) {
        int r = i >> 4, kc = (i & 15) * 4;
        float4 v = make_float4(0.f, 0.f, 0.f, 0.f);
        int gr = row0 + r;
        if (gr < N) v = *(const float4*)(Xf + (size_t)gr * F + kc);
        XT[(kc + 0) * XT_PAD + r] = v.x;
        XT[(kc + 1) * XT_PAD + r] = v.y;
        XT[(kc + 2) * XT_PAD + r] = v.z;
        XT[(kc + 3) * XT_PAD + r] = v.w;
    }
    __syncthreads();
    int ty = t >> 3, tx = t & 7;
    float acc[4][8];
#pragma unroll
    for (int i = 0; i < 4; ++i)
#pragma unroll
        for (int j = 0; j < 8; ++j) acc[i][j] = 0.f;
#pragma unroll 4
    for (int k = 0; k < 64; ++k) {
        float4 xr = *(const float4*)&XT[k * XT_PAD + ty * 4];
        float4 w0 = *(const float4*)&Ws[k * 64 + tx * 8];
        float4 w1 = *(const float4*)&Ws[k * 64 + tx * 8 + 4];
        const float* xv = &xr.x;
#pragma unroll
        for (int i = 0; i < 4; ++i) {
            float xs = xv[i];
            acc[i][0] += xs * w0.x; acc[i][1] += xs * w0.y;
            acc[i][2] += xs * w0.z; acc[i][3] += xs * w0.w;
            acc[i][4] += xs * w1.x; acc[i][5] += xs * w1.y;
            acc[i][6] += xs * w1.z; acc[i][7] += xs * w1.w;
        }
    }
#pragma unroll
    for (int i = 0; i < 4; ++i) {
        int gr = row0 + ty * 4 + i;
        if (gr >= N) continue;
        __half2 h[4];
#pragma unroll
        for (int j = 0; j < 4; ++j)
            h[j] = __floats2half2_rn(acc[i][2 * j], acc[i][2 * j + 1]);
        *reinterpret_cast<uint4*>(Y + (size_t)gr * 32 + tx * 4) =
            *reinterpret_cast<uint4*>(h);
    }
}

// ---- B: per-bucket CSR build, 1024 threads. Segments padded to 4-slot (16 B)
// alignment. Emits desc(start,deg,dinv), csr_src, and scales this bucket's g1
// rows in place by dinv.
__global__ __launch_bounds__(1024) void build_bucket(const unsigned* __restrict__ part,
                                                     const unsigned* __restrict__ bcnt,
                                                     uint4* __restrict__ desc,
                                                     int* __restrict__ csr_src,
                                                     uint4* __restrict__ G,   // g1, scaled in place
                                                     int N) {
    __shared__ unsigned cnt[256], off[256], cur[256];
    __shared__ float dvl[256];
    int t = threadIdx.x;
    int b = blockIdx.x;
    unsigned m0 = (unsigned)b << CAPSH;
    unsigned m1 = m0 + min(bcnt[b], (unsigned)CAP);
    if (t < 256) cnt[t] = 0;
    __syncthreads();
    for (unsigned j = m0 + t; j < m1; j += 1024)
        atomicAdd(&cnt[part[j] >> 24], 1u);
    __syncthreads();
    if (t < 256) off[t] = (cnt[t] + 3u) & ~3u;   // pad segments to 4 slots
    __syncthreads();
    for (int o = 1; o < 256; o <<= 1) {
        unsigned add = 0;
        if (t < 256 && t >= o) add = off[t - o];
        __syncthreads();
        if (t < 256) off[t] += add;
        __syncthreads();
    }
    unsigned excl = 0;
    if (t < 256) excl = t ? off[t - 1] : 0u;
    __syncthreads();                 // all inclusive-scan reads done before overwrite
    int v0 = b << 8;
    if (t < 256) {
        off[t] = excl;
        cur[t] = 0;
        unsigned c = cnt[t];
        float di = rsqrtf((float)(c + 1u));
        dvl[t] = di;
        int v = v0 + t;
        if (v < N)
            desc[v] = make_uint4(m0 + excl, c, __float_as_uint(di), 0u);
    }
    __syncthreads();
    for (unsigned j = m0 + t; j < m1; j += 1024) {
        unsigned p = part[j];
        unsigned d = p >> 24;
        unsigned pos = atomicAdd(&cur[d], 1u);
        csr_src[m0 + off[d] + pos] = (int)(p & 0xFFFFFFu);
    }
    // ---- scale this bucket's 256 g1 rows by dinv (coalesced uint4 stream) ----
#pragma unroll
    for (int k = 0; k < 2; ++k) {
        int idx = t + k * 1024;           // uint4 index within bucket (2048 total)
        int r = idx >> 3;
        int vv = v0 + r;
        if (vv >= N) continue;
        float dv = dvl[r];
        uint4 u = G[(size_t)v0 * 8 + idx];
        __half2* hp = (__half2*)&u;
#pragma unroll
        for (int q = 0; q < 4; ++q) {
            float2 f = __half22float2(hp[q]);
            hp[q] = __floats2half2_rn(f.x * dv, f.y * dv);
        }
        G[(size_t)v0 * 8 + idx] = u;
    }
}

__device__ __forceinline__ void acc8(float* a, const uint4& u) {
    const __half2* hp = reinterpret_cast<const __half2*>(&u);
#pragma unroll
    for (int q = 0; q < 4; ++q) {
        float2 f = __half22float2(hp[q]);
        a[2 * q] += f.x;
        a[2 * q + 1] += f.y;
    }
}

// ---- C FUSED: out1[v] = relu(dinv_v * (sum g1[s] + g1[v]) + b1) ; g2 = (out1@W2)*dinv ----
__global__ __launch_bounds__(256, 4) void gather_mm(const int* __restrict__ csr_src,
                                                    const uint4* __restrict__ desc,
                                                    const uint4* __restrict__ G,
                                                    const float* __restrict__ bias,
                                                    const float* __restrict__ W,
                                                    __half* __restrict__ Y, int N) {
    __shared__ float Ws[64 * 64];     // 16 KB
    __shared__ __half XT[64 * 72];    // 9 KB
    __shared__ float dvs[64];
    int t = threadIdx.x;
    for (int i = t; i < 1024; i += 256)
        ((float4*)Ws)[i] = ((const float4*)W)[i];
    int v0 = blockIdx.x * GMN;
    {   // ---- phase 1: gather (int4 index loads; r0 is 16 B aligned) ----
        int grp = t >> 2, l4 = t & 3;
        int v = v0 + grp;
        float acc[16];
#pragma unroll
        for (int i = 0; i < 16; ++i) acc[i] = 0.f;
        float dv = 0.f;
        if (v < N) {
            uint4 nd = desc[v];
            unsigned r0 = nd.x, r1 = nd.x + nd.y;
            dv = __uint_as_float(nd.z);
            size_t gb = (size_t)v * 8 + l4 * 2;
            uint4 sa = G[gb], sb = G[gb + 1];   // self-loop term
            acc8(acc, sa); acc8(acc + 8, sb);
            unsigned j = r0;
            for (; j + 4 <= r1; j += 4) {
                int4 s4 = *(const int4*)(csr_src + j);
                const int s[4] = { s4.x, s4.y, s4.z, s4.w };
                uint4 u[4][2];
#pragma unroll
                for (int i = 0; i < 4; ++i) {
                    size_t base = (size_t)s[i] * 8 + l4 * 2;
                    u[i][0] = G[base]; u[i][1] = G[base + 1];
                }
#pragma unroll
                for (int i = 0; i < 4; ++i) { acc8(acc, u[i][0]); acc8(acc + 8, u[i][1]); }
            }
            for (; j < r1; ++j) {
                size_t base = (size_t)csr_src[j] * 8 + l4 * 2;
                uint4 a = G[base], b = G[base + 1];
                acc8(acc, a); acc8(acc + 8, b);
            }
        }
        if (l4 == 0) dvs[grp] = dv;
        __half h[16];
#pragma unroll
        for (int q = 0; q < 4; ++q) {
            float4 bb = ((const float4*)bias)[l4 * 4 + q];
            float r0_ = fmaxf(acc[4 * q + 0] * dv + bb.x, 0.f);
            float r1_ = fmaxf(acc[4 * q + 1] * dv + bb.y, 0.f);
            float r2_ = fmaxf(acc[4 * q + 2] * dv + bb.z, 0.f);
            float r3_ = fmaxf(acc[4 * q + 3] * dv + bb.w, 0.f);
            ((__half2*)h)[2 * q + 0] = __floats2half2_rn(r0_, r1_);
            ((__half2*)h)[2 * q + 1] = __floats2half2_rn(r2_, r3_);
        }
        *(uint4*)&XT[grp * 72 + l4 * 16] = ((uint4*)h)[0];
        *(uint4*)&XT[grp * 72 + l4 * 16 + 8] = ((uint4*)h)[1];
    }
    __syncthreads();
    // ---- phase 2: mm (2 rows x 8 cols per thread) ----
    int tx = t & 7, ty = t >> 3;
    const __half2* Xa = (const __half2*)&XT[ty * 72];
    const __half2* Xb = (const __half2*)&XT[(ty + 32) * 72];
    float a0[8], a1[8];
#pragma unroll
    for (int i = 0; i < 8; ++i) { a0[i] = 0.f; a1[i] = 0.f; }
#pragma unroll 4
    for (int k2 = 0; k2 < 32; ++k2) {
        float2 f0 = __half22float2(Xa[k2]);
        float2 f1 = __half22float2(Xb[k2]);
        int k = 2 * k2;
        float4 w00 = *(const float4*)&Ws[k * 64 + tx * 8];
        float4 w01 = *(const float4*)&Ws[k * 64 + tx * 8 + 4];
        float4 w10 = *(const float4*)&Ws[(k + 1) * 64 + tx * 8];
        float4 w11 = *(const float4*)&Ws[(k + 1) * 64 + tx * 8 + 4];
        a0[0] += f0.x * w00.x + f0.y * w10.x; a0[1] += f0.x * w00.y + f0.y * w10.y;
        a0[2] += f0.x * w00.z + f0.y * w10.z; a0[3] += f0.x * w00.w + f0.y * w10.w;
        a0[4] += f0.x * w01.x + f0.y * w11.x; a0[5] += f0.x * w01.y + f0.y * w11.y;
        a0[6] += f0.x * w01.z + f0.y * w11.z; a0[7] += f0.x * w01.w + f0.y * w11.w;
        a1[0] += f1.x * w00.x + f1.y * w10.x; a1[1] += f1.x * w00.y + f1.y * w10.y;
        a1[2] += f1.x * w00.z + f1.y * w10.z; a1[3] += f1.x * w00.w + f1.y * w10.w;
        a1[4] += f1.x * w01.x + f1.y * w11.x; a1[5] += f1.x * w01.y + f1.y * w11.y;
        a1[6] += f1.x * w01.z + f1.y * w11.z; a1[7] += f1.x * w01.w + f1.y * w11.w;
    }
#pragma unroll
    for (int half_ = 0; half_ < 2; ++half_) {
        int r = ty + half_ * 32;
        int v = v0 + r;
        if (v >= N) continue;
        float dv = dvs[r];
        const float* a = half_ ? a1 : a0;
        __half2 h[4];
#pragma unroll
        for (int q = 0; q < 4; ++q)
            h[q] = __floats2half2_rn(a[2 * q] * dv, a[2 * q + 1] * dv);
        *(uint4*)(Y + (size_t)v * F + tx * 8) = *reinterpret_cast<uint4*>(h);
    }
}

// ---- D: final gather: out[v] = dinv[v]*(sum g2[s] + g2[v]) + b2 ; fp32 out
// (non-temporal output stores: don't evict the g2 table from L2).
#define ACCUM8(u) { \
    const __half2* hp = reinterpret_cast<const __half2*>(&(u)); \
    _Pragma("unroll") \
    for (int q = 0; q < 4; ++q) { \
        float2 f = __half22float2(hp[q]); \
        acc[2 * q] += f.x; acc[2 * q + 1] += f.y; } }

__global__ __launch_bounds__(256) void gather_out(const int* __restrict__ csr_src,
                                                  const uint4* __restrict__ desc,
                                                  const uint4* __restrict__ G,
                                                  const float* __restrict__ bias,
                                                  float* __restrict__ O, int N) {
    int gid = blockIdx.x * 256 + threadIdx.x;
    int v = gid >> 3;
    if (v >= N) return;
    int l8 = gid & 7;
    uint4 nd = desc[v];
    unsigned r0 = nd.x;
    unsigned r1 = r0 + nd.y;
    float dv = __uint_as_float(nd.z);
    float acc[8];
#pragma unroll
    for (int i = 0; i < 8; ++i) acc[i] = 0.f;
    {
        uint4 u = G[(size_t)v * 8 + l8];  // self-loop term
        ACCUM8(u)
    }
    unsigned j = r0;   // 16 B aligned
    for (; j + 8 <= r1; j += 8) {
        int4 sa = *(const int4*)(csr_src + j);
        int4 sb = *(const int4*)(csr_src + j + 4);
        const int s[8] = { sa.x, sa.y, sa.z, sa.w, sb.x, sb.y, sb.z, sb.w };
        uint4 u[8];
#pragma unroll
        for (int i = 0; i < 8; ++i) u[i] = G[(size_t)s[i] * 8 + l8];
#pragma unroll
        for (int i = 0; i < 8; ++i) ACCUM8(u[i])
    }
    if (j + 4 <= r1) {
        int4 sa = *(const int4*)(csr_src + j);
        const int s[4] = { sa.x, sa.y, sa.z, sa.w };
        uint4 u[4];
#pragma unroll
        for (int i = 0; i < 4; ++i) u[i] = G[(size_t)s[i] * 8 + l8];
#pragma unroll
        for (int i = 0; i < 4; ++i) ACCUM8(u[i])
        j += 4;
    }
    for (; j < r1; ++j) {
        uint4 u = G[(size_t)csr_src[j] * 8 + l8];
        ACCUM8(u)
    }
    float4 bb0 = ((const float4*)bias)[l8 * 2];
    float4 bb1 = ((const float4*)bias)[l8 * 2 + 1];
    f4nt* o = (f4nt*)O + (size_t)v * 16 + l8 * 2;
    f4nt o0 = { acc[0] * dv + bb0.x, acc[1] * dv + bb0.y,
                acc[2] * dv + bb0.z, acc[3] * dv + bb0.w };
    f4nt o1 = { acc[4] * dv + bb1.x, acc[5] * dv + bb1.y,
                acc[6] * dv + bb1.z, acc[7] * dv + bb1.w };
    __builtin_nontemporal_store(o0, o);
    __builtin_nontemporal_store(o1, o + 1);
}
#undef ACCUM8

extern "C" void kernel_launch(void* const* d_in, const int* in_sizes, int n_in,
                              void* d_out, int out_size, void* d_ws, size_t ws_size,
                              hipStream_t stream) {
    const float* x  = (const float*)d_in[0];
    const int*   ei = (const int*)d_in[1];
    const float* W1 = (const float*)d_in[2];
    const float* b1 = (const float*)d_in[3];
    const float* W2 = (const float*)d_in[4];
    const float* b2 = (const float*)d_in[5];
    int N = in_sizes[0] / F;
    int E = in_sizes[1] / 2;
    const int* srcp = ei;
    const int* dstp = ei + E;
    float* out = (float*)d_out;
    int NB = (N + 255) >> 8;

    char* w = (char*)d_ws;
    auto align = [](size_t s) { return (s + 255) / 256 * 256; };
    unsigned* bcnt    = (unsigned*)w;  w += align(NBMAX * 4);
    unsigned* part    = (unsigned*)w;  w += align((size_t)NB << (CAPSH + 2));
    int*      csrsrc  = (int*)w;       w += align((size_t)NB << (CAPSH + 2));
    uint4*    desc    = (uint4*)w;     w += align((size_t)N * 16);
    __half2*  bufA    = (__half2*)w;   w += align((size_t)N * F * 2);  // g1 (f16)
    __half*   bufC    = (__half*)w;    w += align((size_t)N * F * 2);  // g2 (f16)

    hipMemsetAsync(bcnt, 0, (size_t)NB * 4, stream);

    int PG = (E + CHUNK - 1) / CHUNK;
    int MMG = (N + MMROWS - 1) / MMROWS;
    // A: partition edges (blocks 0..PG) + g1 = x@W1 unscaled (blocks PG..PG+MMG)
    part_mm<<<PG + MMG, 256, 0, stream>>>(srcp, dstp, bcnt, part, E, NB, PG,
                                          x, W1, (__half2*)bufA, N);
    // B: CSR build (4-aligned segments) + desc + in-place dinv scaling of g1
    build_bucket<<<NB, 1024, 0, stream>>>(part, bcnt, desc, csrsrc, (uint4*)bufA, N);
    // C: out1 = relu(dinv*(sum g1)+b1); g2 = (out1@W2)*dinv
    gather_mm<<<(N + GMN - 1) / GMN, 256, 0, stream>>>(csrsrc, desc, (const uint4*)bufA, b1, W2, bufC, N);
    // D: out = dinv*(sum g2) + b2 (NT stores)
    gather_out<<<(int)(((size_t)N * 8 + 255) / 256), 256, 0, stream>>>(
        csrsrc, desc, (const uint4*)bufC, b2, out, N);
}